// Round 12
// baseline (68.267 us; speedup 1.0000x reference)
//
#include <hip/hip_runtime.h>
#include <hip/hip_bf16.h>

#define NN    4096
#define FIN   512
#define NH1   128
#define NH    4
#define NH2   256
#define NH3   64
#define CAP   64          // max neighbors per row (mean ~17)
#define ALPHA 0.2f

typedef float f32x4 __attribute__((ext_vector_type(4)));
typedef __bf16 bf16x8 __attribute__((ext_vector_type(8)));

__device__ __forceinline__ unsigned short f2bf(float f) {
    union { float f; unsigned u; } x; x.f = f;
    unsigned r = x.u + 0x7fff + ((x.u >> 16) & 1);   // RNE (finite inputs)
    return (unsigned short)(r >> 16);
}
__device__ __forceinline__ float bf2f(ushort u) {
    union { unsigned u; float f; } x; x.u = ((unsigned)u) << 16;
    return x.f;
}
__device__ __forceinline__ float bflo(unsigned w) {
    union { unsigned u; float f; } x; x.u = w << 16; return x.f;
}
__device__ __forceinline__ float bfhi(unsigned w) {
    union { unsigned u; float f; } x; x.u = w & 0xffff0000u; return x.f;
}

// ---------------------------------------------------------------------------
// k_conv: weight/input conversions + zero s1/s2
// ---------------------------------------------------------------------------
#define C_X     2048                // x -> bf16 (2M elems, 4/thread)
#define C_WATT  (C_X + 1024)        // W_att repack+cvt (256K elems)
#define C_W1T   (C_WATT + 512)      // W1 transpose+cvt (128K elems)
#define C_W2B   (C_W1T + 16)        // W2 flat cvt (16K elems, 4/thread)
#define C_Z     (C_W2B + 32)        // zero s1s2 (32K floats, float4/thread)

__global__ __launch_bounds__(256) void k_conv(
    const float* __restrict__ x, ushort* __restrict__ xb,
    const float* __restrict__ W_att, ushort* __restrict__ Wattb,
    const float* __restrict__ W1, ushort* __restrict__ W1t,
    const float* __restrict__ W2, ushort* __restrict__ W2b,
    float* __restrict__ s1s2) {
    int bid = blockIdx.x;
    int tid = threadIdx.x;
    if (bid < C_X) {
        int i = (bid * 256 + tid) * 4;                    // exact: 2M elems
        float4 v = *reinterpret_cast<const float4*>(x + i);
        ushort4 o;
        o.x = f2bf(v.x); o.y = f2bf(v.y); o.z = f2bf(v.z); o.w = f2bf(v.w);
        *reinterpret_cast<ushort4*>(xb + i) = o;
    } else if (bid < C_WATT) {
        int idx = (bid - C_X) * 256 + tid;                // col*512 + f
        int col = idx >> 9, f = idx & 511;
        int h = col >> 7, o = col & 127;
        Wattb[idx] = f2bf(W_att[h * (FIN * NH1) + f * NH1 + o]);
    } else if (bid < C_W1T) {
        int idx = (bid - C_WATT) * 256 + tid;             // c*512 + r, (256x512)
        int c = idx >> 9, r = idx & 511;
        W1t[idx] = f2bf(W1[(size_t)r * NH2 + c]);
    } else if (bid < C_W2B) {
        int i = ((bid - C_W1T) * 256 + tid) * 4;          // 16K elems flat
        float4 v = *reinterpret_cast<const float4*>(W2 + i);
        ushort4 o;
        o.x = f2bf(v.x); o.y = f2bf(v.y); o.z = f2bf(v.z); o.w = f2bf(v.w);
        *reinterpret_cast<ushort4*>(W2b + i) = o;
    } else {
        int i = (bid - C_W2B) * 256 + tid;                // 8192 float4 = 32K floats
        f32x4 z = {0.f, 0.f, 0.f, 0.f};
        *reinterpret_cast<f32x4*>(s1s2 + i * 4) = z;
    }
}

// ---------------------------------------------------------------------------
// K2: fused gemm1 + CSR. blocks [0,512): 64x64 MFMA tiles of Whb = xb@Wattb^T
// (+ fused s1/s2 scores); blocks [512, 4608): CSR build for row bid-512.
// The 64MB adj HBM read overlaps the MFMA compute on co-resident CUs.
// ---------------------------------------------------------------------------
__global__ __launch_bounds__(256) void k_g1csr(const ushort* __restrict__ A,
                                               const ushort* __restrict__ Bt,
                                               ushort* __restrict__ Cb,
                                               const float* __restrict__ av,
                                               float* __restrict__ s1,
                                               float* __restrict__ s2,
                                               const float* __restrict__ adj,
                                               int* __restrict__ nbr,
                                               int* __restrict__ cnt) {
    __shared__ __align__(16) char smem[32768];
    const int bid = blockIdx.x;
    const int tid = threadIdx.x;
    const int wid = tid >> 6;
    const int lane = tid & 63;

    if (bid < 512) {
        // ---- GEMM tile: M=4096,N=512,K=512; bx = bid&7, by = bid>>3 ----
        const int N = NH * NH1, K = FIN;
        ushort* As = (ushort*)smem;             // 2 x 4096 ushort
        ushort* Bs = (ushort*)(smem + 16384);   // 2 x 4096 ushort
        const int row0 = (bid >> 3) * 64;
        const int col0 = (bid & 7) * 64;
        const int wr = wid >> 1, wc = wid & 1;
        f32x4 acc[2][2] = {};

        auto stage = [&](int buf, int k0) {
            #pragma unroll
            for (int j = 0; j < 2; ++j) {
                int ci = j * 256 + tid;
                int r = ci >> 3;
                int sc = (ci & 7) ^ (r & 7);
                const ushort* ga = A + (size_t)(row0 + r) * K + k0 + sc * 8;
                const ushort* gb = Bt + (size_t)(col0 + r) * K + k0 + sc * 8;
                ushort* la = As + buf * 4096 + ci * 8;
                ushort* lb = Bs + buf * 4096 + ci * 8;
                __builtin_amdgcn_global_load_lds(
                    (const __attribute__((address_space(1))) unsigned int*)ga,
                    (__attribute__((address_space(3))) unsigned int*)la, 16, 0, 0);
                __builtin_amdgcn_global_load_lds(
                    (const __attribute__((address_space(1))) unsigned int*)gb,
                    (__attribute__((address_space(3))) unsigned int*)lb, 16, 0, 0);
            }
        };

        stage(0, 0);
        __syncthreads();
        int cur = 0;
        for (int t = 0; t < K / 64; ++t) {
            if (t + 1 < K / 64) stage(cur ^ 1, (t + 1) * 64);
            #pragma unroll
            for (int kk = 0; kk < 2; ++kk) {
                bf16x8 af[2], bfv[2];
                #pragma unroll
                for (int m = 0; m < 2; ++m) {
                    int r = wr * 32 + m * 16 + (lane & 15);
                    int kc = kk * 4 + (lane >> 4);
                    int off = r * 64 + (((kc ^ (r & 7)) & 7) << 3);
                    af[m] = *reinterpret_cast<const bf16x8*>(&As[cur * 4096 + off]);
                }
                #pragma unroll
                for (int n = 0; n < 2; ++n) {
                    int c = wc * 32 + n * 16 + (lane & 15);
                    int kc = kk * 4 + (lane >> 4);
                    int off = c * 64 + (((kc ^ (c & 7)) & 7) << 3);
                    bfv[n] = *reinterpret_cast<const bf16x8*>(&Bs[cur * 4096 + off]);
                }
                #pragma unroll
                for (int m = 0; m < 2; ++m)
                    #pragma unroll
                    for (int n = 0; n < 2; ++n)
                        acc[m][n] = __builtin_amdgcn_mfma_f32_16x16x32_bf16(af[m], bfv[n], acc[m][n], 0, 0, 0);
            }
            __syncthreads();
            cur ^= 1;
        }
        #pragma unroll
        for (int m = 0; m < 2; ++m)
            #pragma unroll
            for (int n = 0; n < 2; ++n) {
                int col = col0 + wc * 32 + n * 16 + (lane & 15);
                #pragma unroll
                for (int j2 = 0; j2 < 4; ++j2) {
                    int row = row0 + wr * 32 + m * 16 + (lane >> 4) * 4 + j2;
                    Cb[(size_t)row * N + col] = f2bf(acc[m][n][j2]);
                }
            }
        // fused scores
        int h = col0 >> 7;
        float a1v[2], a2v[2];
        #pragma unroll
        for (int n = 0; n < 2; ++n) {
            int colh = (col0 & 127) + wc * 32 + n * 16 + (lane & 15);
            a1v[n] = av[h * 256 + colh];
            a2v[n] = av[h * 256 + 128 + colh];
        }
        #pragma unroll
        for (int m = 0; m < 2; ++m)
            #pragma unroll
            for (int j2 = 0; j2 < 4; ++j2) {
                float v1 = acc[m][0][j2] * a1v[0] + acc[m][1][j2] * a1v[1];
                float v2 = acc[m][0][j2] * a2v[0] + acc[m][1][j2] * a2v[1];
                #pragma unroll
                for (int off = 1; off < 16; off <<= 1) {
                    v1 += __shfl_xor(v1, off);
                    v2 += __shfl_xor(v2, off);
                }
                if ((lane & 15) == 0) {
                    int row = row0 + wr * 32 + m * 16 + (lane >> 4) * 4 + j2;
                    atomicAdd(&s1[h * NN + row], v1);
                    atomicAdd(&s2[h * NN + row], v2);
                }
            }
    } else {
        // ---- CSR build for row = bid - 512 ----
        int* lds_list = (int*)smem;               // [4][64]
        int* lds_cnt  = (int*)(smem + 1024);      // [4]
        int row = bid - 512;
        const uint4* arow = (const uint4*)(adj + (size_t)row * NN);
        uint4 v[4];
        #pragma unroll
        for (int it = 0; it < 4; ++it) v[it] = arow[wid * 256 + it * 64 + lane];
        const unsigned long long below = (1ull << lane) - 1ull;
        int base = 0;
        #pragma unroll
        for (int it = 0; it < 4; ++it) {
            unsigned long long b0 = __ballot(v[it].x != 0u);
            unsigned long long b1 = __ballot(v[it].y != 0u);
            unsigned long long b2 = __ballot(v[it].z != 0u);
            unsigned long long b3 = __ballot(v[it].w != 0u);
            int pre = __popcll(b0 & below) + __popcll(b1 & below) +
                      __popcll(b2 & below) + __popcll(b3 & below);
            int col0 = wid * 1024 + it * 256 + lane * 4;
            int pos = base + pre;
            if (v[it].x != 0u) { if (pos < 64) lds_list[wid * 64 + pos] = col0;     ++pos; }
            if (v[it].y != 0u) { if (pos < 64) lds_list[wid * 64 + pos] = col0 + 1; ++pos; }
            if (v[it].z != 0u) { if (pos < 64) lds_list[wid * 64 + pos] = col0 + 2; ++pos; }
            if (v[it].w != 0u) { if (pos < 64) lds_list[wid * 64 + pos] = col0 + 3; ++pos; }
            base += __popcll(b0) + __popcll(b1) + __popcll(b2) + __popcll(b3);
        }
        if (lane == 0) lds_cnt[wid] = base;
        __syncthreads();
        int c0 = lds_cnt[0], c1 = lds_cnt[1], c2 = lds_cnt[2], c3 = lds_cnt[3];
        int off = (wid > 0 ? c0 : 0) + (wid > 1 ? c1 : 0) + (wid > 2 ? c2 : 0);
        int my = lds_cnt[wid]; if (my > 64) my = 64;
        int* outp = nbr + row * CAP;
        if (lane < my) {
            int gpos = off + lane;
            if (gpos < CAP) outp[gpos] = lds_list[wid * 64 + lane];
        }
        if (tid == 0) {
            int tot = c0 + c1 + c2 + c3;
            cnt[row] = tot < CAP ? tot : CAP;
        }
    }
}

// ---------------------------------------------------------------------------
// bf16 MFMA GEMM (gemm2): BM=32, BN=64, BK=64, dbuf — R11-verified
// ---------------------------------------------------------------------------
__global__ __launch_bounds__(256) void k_gemm2(const ushort* __restrict__ A,
                                               const ushort* __restrict__ Bt,
                                               ushort* __restrict__ Cb,
                                               int M, int N, int K) {
    __shared__ ushort As[2][32 * 64];
    __shared__ ushort Bs[2][64 * 64];
    const int tid = threadIdx.x;
    const int wid = tid >> 6;
    const int lane = tid & 63;
    const int row0 = blockIdx.y * 32;
    const int col0 = blockIdx.x * 64;
    const int wr = wid >> 1, wc = wid & 1;

    f32x4 acc[2] = {};
    const int nt = K / 64;

    auto stage = [&](int buf, int k0) {
        {
            int ci = tid;
            int r = ci >> 3;
            int sc = (ci & 7) ^ (r & 7);
            const ushort* ga = A + (size_t)(row0 + r) * K + k0 + sc * 8;
            ushort* la = &As[buf][(size_t)ci * 8];
            __builtin_amdgcn_global_load_lds(
                (const __attribute__((address_space(1))) unsigned int*)ga,
                (__attribute__((address_space(3))) unsigned int*)la, 16, 0, 0);
        }
        #pragma unroll
        for (int j = 0; j < 2; ++j) {
            int ci = j * 256 + tid;
            int r = ci >> 3;
            int sc = (ci & 7) ^ (r & 7);
            const ushort* gb = Bt + (size_t)(col0 + r) * K + k0 + sc * 8;
            ushort* lb = &Bs[buf][(size_t)ci * 8];
            __builtin_amdgcn_global_load_lds(
                (const __attribute__((address_space(1))) unsigned int*)gb,
                (__attribute__((address_space(3))) unsigned int*)lb, 16, 0, 0);
        }
    };

    stage(0, 0);
    __syncthreads();
    int cur = 0;
    for (int t = 0; t < nt; ++t) {
        if (t + 1 < nt) stage(cur ^ 1, (t + 1) * 64);
        #pragma unroll
        for (int kk = 0; kk < 2; ++kk) {
            bf16x8 af, bfv[2];
            {
                int r = wr * 16 + (lane & 15);
                int kc = kk * 4 + (lane >> 4);
                int off = r * 64 + (((kc ^ (r & 7)) & 7) << 3);
                af = *reinterpret_cast<const bf16x8*>(&As[cur][off]);
            }
            #pragma unroll
            for (int n = 0; n < 2; ++n) {
                int c = wc * 32 + n * 16 + (lane & 15);
                int kc = kk * 4 + (lane >> 4);
                int off = c * 64 + (((kc ^ (c & 7)) & 7) << 3);
                bfv[n] = *reinterpret_cast<const bf16x8*>(&Bs[cur][off]);
            }
            #pragma unroll
            for (int n = 0; n < 2; ++n)
                acc[n] = __builtin_amdgcn_mfma_f32_16x16x32_bf16(af, bfv[n], acc[n], 0, 0, 0);
        }
        __syncthreads();
        cur ^= 1;
    }
    #pragma unroll
    for (int n = 0; n < 2; ++n) {
        int col = col0 + wc * 32 + n * 16 + (lane & 15);
        #pragma unroll
        for (int j2 = 0; j2 < 4; ++j2) {
            int row = row0 + wr * 16 + (lane >> 4) * 4 + j2;
            Cb[(size_t)row * N + col] = f2bf(acc[n][j2]);
        }
    }
}

// ---------------------------------------------------------------------------
// attention: softmax + aggregate (8-way unrolled gather) -> xrb
// ---------------------------------------------------------------------------
__global__ __launch_bounds__(256) void k_attn(const ushort* __restrict__ Whb,
                                              const float* __restrict__ s1,
                                              const float* __restrict__ s2,
                                              const int* __restrict__ nbr,
                                              const int* __restrict__ cnt,
                                              ushort* __restrict__ xrb) {
    int n = blockIdx.x;
    int h = threadIdx.x >> 6;
    int lane = threadIdx.x & 63;
    int c = cnt[n];
    const int* nb = nbr + n * CAP;
    int m = (lane < c) ? nb[lane] : 0;
    float e = -1e30f;
    float s1n = s1[h * NN + n];
    if (lane < c) {
        float t = s1n + s2[h * NN + m];
        e = (t >= 0.0f) ? t : ALPHA * t;
    }
    float mx = e;
    #pragma unroll
    for (int off = 32; off; off >>= 1) mx = fmaxf(mx, __shfl_xor(mx, off));
    float p = (lane < c) ? __expf(e - mx) : 0.0f;
    float s = p;
    #pragma unroll
    for (int off = 32; off; off >>= 1) s += __shfl_xor(s, off);
    p /= s;
    const ushort* wb = Whb + h * 128 + 2 * lane;
    float acc0 = 0.0f, acc1 = 0.0f;
    int cp8 = (c + 7) & ~7;
    for (int j = 0; j < cp8; j += 8) {
        float pj[8]; int mj[8]; unsigned wj[8];
        #pragma unroll
        for (int u = 0; u < 8; ++u) {
            pj[u] = __shfl(p, j + u);
            mj[u] = __shfl(m, j + u);
        }
        #pragma unroll
        for (int u = 0; u < 8; ++u)
            wj[u] = *reinterpret_cast<const unsigned*>(wb + (size_t)mj[u] * 512);
        #pragma unroll
        for (int u = 0; u < 8; ++u) {
            acc0 = fmaf(pj[u], bflo(wj[u]), acc0);
            acc1 = fmaf(pj[u], bfhi(wj[u]), acc1);
        }
    }
    unsigned ow = (unsigned)f2bf(fmaxf(acc0, 0.0f)) | ((unsigned)f2bf(fmaxf(acc1, 0.0f)) << 16);
    *reinterpret_cast<unsigned*>(xrb + (size_t)n * 512 + h * 128 + 2 * lane) = ow;
}

// ---------------------------------------------------------------------------
// Fused: g1 = relu(nbrsum(y1b)) in LDS, then y2[n] = g1 @ W2  (f32 out)
// ---------------------------------------------------------------------------
__global__ __launch_bounds__(256) void k_g1y2(const ushort* __restrict__ y1b,
                                              const int* __restrict__ nbr,
                                              const int* __restrict__ cnt,
                                              const ushort* __restrict__ W2b,
                                              float* __restrict__ y2) {
    __shared__ float g1s[NH2];
    __shared__ float part[4][NH3];
    int n = blockIdx.x;
    int tid = threadIdx.x;
    int c = cnt[n];
    const int* nb = nbr + n * CAP;
    if (tid < 128) {
        float acc0 = 0.0f, acc1 = 0.0f;
        const ushort* yb = y1b + 2 * tid;
        for (int j = 0; j < c; j += 8) {
            int idx[8]; float f[8]; unsigned w[8];
            #pragma unroll
            for (int u = 0; u < 8; ++u) {
                idx[u] = nb[(j + u < c) ? j + u : j];
                f[u] = (j + u < c) ? 1.f : 0.f;
            }
            #pragma unroll
            for (int u = 0; u < 8; ++u)
                w[u] = *reinterpret_cast<const unsigned*>(yb + (size_t)idx[u] * NH2);
            #pragma unroll
            for (int u = 0; u < 8; ++u) {
                acc0 = fmaf(f[u], bflo(w[u]), acc0);
                acc1 = fmaf(f[u], bfhi(w[u]), acc1);
            }
        }
        g1s[2 * tid]     = fmaxf(acc0, 0.0f);
        g1s[2 * tid + 1] = fmaxf(acc1, 0.0f);
    }
    __syncthreads();
    int q = tid >> 6, col = tid & 63;
    float acc = 0.0f;
    #pragma unroll 8
    for (int i = 0; i < 64; ++i) {
        int k = q * 64 + i;
        acc = fmaf(g1s[k], bf2f(W2b[k * NH3 + col]), acc);
    }
    part[q][col] = acc;
    __syncthreads();
    if (tid < 64)
        y2[(size_t)n * NH3 + tid] = part[0][tid] + part[1][tid] + part[2][tid] + part[3][tid];
}

// ---------------------------------------------------------------------------
// final: 4 nodes/block (wave per node); g2 = nbrsum(y2); out = [g2, softmax]
// ---------------------------------------------------------------------------
__global__ __launch_bounds__(256) void k_final(const float* __restrict__ Y2,
                                               const int* __restrict__ nbr,
                                               const int* __restrict__ cnt,
                                               float* __restrict__ out) {
    int n = blockIdx.x * 4 + (threadIdx.x >> 6);
    int lane = threadIdx.x & 63;
    int c = cnt[n];
    const int* nb = nbr + n * CAP;
    float acc = 0.0f;
    for (int j = 0; j < c; j += 8) {
        int idx[8]; float f[8]; float v[8];
        #pragma unroll
        for (int u = 0; u < 8; ++u) {
            idx[u] = nb[(j + u < c) ? j + u : j];
            f[u] = (j + u < c) ? 1.f : 0.f;
        }
        #pragma unroll
        for (int u = 0; u < 8; ++u)
            v[u] = Y2[(size_t)idx[u] * NH3 + lane];
        #pragma unroll
        for (int u = 0; u < 8; ++u)
            acc = fmaf(f[u], v[u], acc);
    }
    out[(size_t)n * NH3 + lane] = acc;
    float mx = acc;
    #pragma unroll
    for (int off = 32; off; off >>= 1) mx = fmaxf(mx, __shfl_xor(mx, off));
    float p = __expf(acc - mx);
    float s = p;
    #pragma unroll
    for (int off = 32; off; off >>= 1) s += __shfl_xor(s, off);
    out[(size_t)NN * NH3 + (size_t)n * NH3 + lane] = p / s;
}

// ---------------------------------------------------------------------------
extern "C" void kernel_launch(void* const* d_in, const int* in_sizes, int n_in,
                              void* d_out, int out_size, void* d_ws, size_t ws_size,
                              hipStream_t stream) {
    const float* x     = (const float*)d_in[0];   // (4096, 512)
    const float* adj   = (const float*)d_in[1];   // (4096, 4096)
    const float* W_att = (const float*)d_in[2];   // (4, 512, 128)
    const float* a     = (const float*)d_in[3];   // (4, 256)
    const float* W1    = (const float*)d_in[4];   // (512, 256)
    const float* W2    = (const float*)d_in[5];   // (256, 64)
    float* out = (float*)d_out;

    char* p = (char*)d_ws;
    ushort* xb    = (ushort*)p; p += (size_t)NN * FIN * 2;           // 4 MB
    ushort* Wattb = (ushort*)p; p += (size_t)FIN * NH * NH1 * 2;     // 0.5 MB
    ushort* W1t   = (ushort*)p; p += (size_t)NH2 * (NH * NH1) * 2;   // 0.25 MB
    ushort* W2b   = (ushort*)p; p += (size_t)NH2 * NH3 * 2;          // 32 KB
    ushort* Whb   = (ushort*)p; p += (size_t)NN * NH * NH1 * 2;      // 4 MB
    float*  s1    = (float*)p;  p += (size_t)NH * NN * 4;
    float*  s2    = (float*)p;  p += (size_t)NH * NN * 4;
    int*    nbr   = (int*)p;    p += (size_t)NN * CAP * 4;           // 1 MB
    int*    cnt   = (int*)p;    p += (size_t)NN * 4;
    ushort* xrb   = (ushort*)p; p += (size_t)NN * NH * NH1 * 2;      // 4 MB
    ushort* y1b   = (ushort*)p; p += (size_t)NN * NH2 * 2;           // 2 MB
    float*  y2    = (float*)p;  p += (size_t)NN * NH3 * 4;           // 1 MB

    // A: conversions + zero s1/s2
    k_conv<<<C_Z, 256, 0, stream>>>(x, xb, W_att, Wattb, W1, W1t, W2, W2b, s1);
    // B: fused gemm1(+scores) and CSR build — adj read overlaps MFMA
    k_g1csr<<<512 + NN, 256, 0, stream>>>(xb, Wattb, Whb, a, s1, s2, adj, nbr, cnt);
    // C: attention -> xrb
    k_attn<<<NN, 256, 0, stream>>>(Whb, s1, s2, nbr, cnt, xrb);
    // D: y1b = xr @ W1  (BM=32; 512 blocks, 2/CU)
    k_gemm2<<<dim3(NH2 / 64, NN / 32), 256, 0, stream>>>(xrb, W1t, y1b, NN, NH2, NH * NH1);
    // E: g1 = relu(nbrsum(y1b)); y2 = g1 @ W2
    k_g1y2<<<NN, 256, 0, stream>>>(y1b, nbr, cnt, W2b, y2);
    // F: g2 + softmax (4 nodes/block)
    k_final<<<NN / 4, 256, 0, stream>>>(y2, nbr, cnt, out);
}

// Round 13
// 66.209 us; speedup vs baseline: 1.0311x; 1.0311x over previous
//
#include <hip/hip_runtime.h>
#include <hip/hip_bf16.h>

#define NN    4096
#define FIN   512
#define NH1   128
#define NH    4
#define NH2   256
#define NH3   64
#define CAP   64          // max neighbors per row (mean ~17)
#define ALPHA 0.2f

typedef float f32x4 __attribute__((ext_vector_type(4)));
typedef __bf16 bf16x8 __attribute__((ext_vector_type(8)));

__device__ __forceinline__ unsigned short f2bf(float f) {
    union { float f; unsigned u; } x; x.f = f;
    unsigned r = x.u + 0x7fff + ((x.u >> 16) & 1);   // RNE (finite inputs)
    return (unsigned short)(r >> 16);
}
__device__ __forceinline__ float bf2f(ushort u) {
    union { unsigned u; float f; } x; x.u = ((unsigned)u) << 16;
    return x.f;
}
__device__ __forceinline__ float bflo(unsigned w) {
    union { unsigned u; float f; } x; x.u = w << 16; return x.f;
}
__device__ __forceinline__ float bfhi(unsigned w) {
    union { unsigned u; float f; } x; x.u = w & 0xffff0000u; return x.f;
}

// ---------------------------------------------------------------------------
// k_conv: weight/input conversions + zero s1/s2
// ---------------------------------------------------------------------------
#define C_X     2048                // x -> bf16 (2M elems, 4/thread)
#define C_WATT  (C_X + 1024)        // W_att repack+cvt (256K elems)
#define C_W1T   (C_WATT + 512)      // W1 transpose+cvt (128K elems)
#define C_W2B   (C_W1T + 16)        // W2 flat cvt (16K elems, 4/thread)
#define C_Z     (C_W2B + 32)        // zero s1s2 (32K floats, float4/thread)

__global__ __launch_bounds__(256) void k_conv(
    const float* __restrict__ x, ushort* __restrict__ xb,
    const float* __restrict__ W_att, ushort* __restrict__ Wattb,
    const float* __restrict__ W1, ushort* __restrict__ W1t,
    const float* __restrict__ W2, ushort* __restrict__ W2b,
    float* __restrict__ s1s2) {
    int bid = blockIdx.x;
    int tid = threadIdx.x;
    if (bid < C_X) {
        int i = (bid * 256 + tid) * 4;                    // exact: 2M elems
        float4 v = *reinterpret_cast<const float4*>(x + i);
        ushort4 o;
        o.x = f2bf(v.x); o.y = f2bf(v.y); o.z = f2bf(v.z); o.w = f2bf(v.w);
        *reinterpret_cast<ushort4*>(xb + i) = o;
    } else if (bid < C_WATT) {
        int idx = (bid - C_X) * 256 + tid;                // col*512 + f
        int col = idx >> 9, f = idx & 511;
        int h = col >> 7, o = col & 127;
        Wattb[idx] = f2bf(W_att[h * (FIN * NH1) + f * NH1 + o]);
    } else if (bid < C_W1T) {
        int idx = (bid - C_WATT) * 256 + tid;             // c*512 + r, (256x512)
        int c = idx >> 9, r = idx & 511;
        W1t[idx] = f2bf(W1[(size_t)r * NH2 + c]);
    } else if (bid < C_W2B) {
        int i = ((bid - C_W1T) * 256 + tid) * 4;          // 16K elems flat
        float4 v = *reinterpret_cast<const float4*>(W2 + i);
        ushort4 o;
        o.x = f2bf(v.x); o.y = f2bf(v.y); o.z = f2bf(v.z); o.w = f2bf(v.w);
        *reinterpret_cast<ushort4*>(W2b + i) = o;
    } else {
        int i = (bid - C_W2B) * 256 + tid;                // 8192 float4 = 32K floats
        f32x4 z = {0.f, 0.f, 0.f, 0.f};
        *reinterpret_cast<f32x4*>(s1s2 + i * 4) = z;
    }
}

// ---------------------------------------------------------------------------
// bf16 MFMA GEMM, BM = 32*MT, BN=64, BK=64, 4 waves, dbuf LDS.
// 1D grid, XCD-coherent remap: by = bid & ((1<<BYBITS)-1), bx = bid >> BYBITS
// -> all blocks sharing an A-row-panel have equal bid%8 (same XCD L2).
// SCORES: fused s1/s2 accumulation from fp32 acc
// ---------------------------------------------------------------------------
template <int SCORES, int MT, int BYBITS>
__global__ __launch_bounds__(256) void k_gemm(const ushort* __restrict__ A,
                                              const ushort* __restrict__ Bt,
                                              ushort* __restrict__ Cb,
                                              const float* __restrict__ av,
                                              float* __restrict__ s1,
                                              float* __restrict__ s2,
                                              int M, int N, int K) {
    __shared__ ushort As[2][32 * MT * 64];
    __shared__ ushort Bs[2][64 * 64];
    const int tid = threadIdx.x;
    const int wid = tid >> 6;
    const int lane = tid & 63;
    const int bid = blockIdx.x;
    const int row0 = (bid & ((1 << BYBITS) - 1)) * (32 * MT);
    const int col0 = (bid >> BYBITS) * 64;
    const int wr = wid >> 1, wc = wid & 1;

    f32x4 acc[MT][2] = {};
    const int nt = K / 64;

    auto stage = [&](int buf, int k0) {
        #pragma unroll
        for (int j = 0; j < MT; ++j) {          // A: MT*256 chunks
            int ci = j * 256 + tid;
            int r = ci >> 3;
            int sc = (ci & 7) ^ (r & 7);
            const ushort* ga = A + (size_t)(row0 + r) * K + k0 + sc * 8;
            ushort* la = &As[buf][(size_t)ci * 8];
            __builtin_amdgcn_global_load_lds(
                (const __attribute__((address_space(1))) unsigned int*)ga,
                (__attribute__((address_space(3))) unsigned int*)la, 16, 0, 0);
        }
        #pragma unroll
        for (int j = 0; j < 2; ++j) {           // B: 512 chunks
            int ci = j * 256 + tid;
            int r = ci >> 3;
            int sc = (ci & 7) ^ (r & 7);
            const ushort* gb = Bt + (size_t)(col0 + r) * K + k0 + sc * 8;
            ushort* lb = &Bs[buf][(size_t)ci * 8];
            __builtin_amdgcn_global_load_lds(
                (const __attribute__((address_space(1))) unsigned int*)gb,
                (__attribute__((address_space(3))) unsigned int*)lb, 16, 0, 0);
        }
    };

    stage(0, 0);
    __syncthreads();
    int cur = 0;
    for (int t = 0; t < nt; ++t) {
        if (t + 1 < nt) stage(cur ^ 1, (t + 1) * 64);
        #pragma unroll
        for (int kk = 0; kk < 2; ++kk) {
            bf16x8 af[MT], bfv[2];
            #pragma unroll
            for (int m = 0; m < MT; ++m) {
                int r = wr * (16 * MT) + m * 16 + (lane & 15);
                int kc = kk * 4 + (lane >> 4);
                int off = r * 64 + (((kc ^ (r & 7)) & 7) << 3);
                af[m] = *reinterpret_cast<const bf16x8*>(&As[cur][off]);
            }
            #pragma unroll
            for (int n = 0; n < 2; ++n) {
                int c = wc * 32 + n * 16 + (lane & 15);
                int kc = kk * 4 + (lane >> 4);
                int off = c * 64 + (((kc ^ (c & 7)) & 7) << 3);
                bfv[n] = *reinterpret_cast<const bf16x8*>(&Bs[cur][off]);
            }
            #pragma unroll
            for (int m = 0; m < MT; ++m)
                #pragma unroll
                for (int n = 0; n < 2; ++n)
                    acc[m][n] = __builtin_amdgcn_mfma_f32_16x16x32_bf16(af[m], bfv[n], acc[m][n], 0, 0, 0);
        }
        __syncthreads();
        cur ^= 1;
    }
    #pragma unroll
    for (int m = 0; m < MT; ++m)
        #pragma unroll
        for (int n = 0; n < 2; ++n) {
            int col = col0 + wc * 32 + n * 16 + (lane & 15);
            #pragma unroll
            for (int j2 = 0; j2 < 4; ++j2) {
                int row = row0 + wr * (16 * MT) + m * 16 + (lane >> 4) * 4 + j2;
                Cb[(size_t)row * N + col] = f2bf(acc[m][n][j2]);
            }
        }
    if (SCORES) {
        int h = col0 >> 7;
        float a1v[2], a2v[2];
        #pragma unroll
        for (int n = 0; n < 2; ++n) {
            int colh = (col0 & 127) + wc * 32 + n * 16 + (lane & 15);
            a1v[n] = av[h * 256 + colh];
            a2v[n] = av[h * 256 + 128 + colh];
        }
        #pragma unroll
        for (int m = 0; m < MT; ++m)
            #pragma unroll
            for (int j2 = 0; j2 < 4; ++j2) {
                float v1 = acc[m][0][j2] * a1v[0] + acc[m][1][j2] * a1v[1];
                float v2 = acc[m][0][j2] * a2v[0] + acc[m][1][j2] * a2v[1];
                #pragma unroll
                for (int off = 1; off < 16; off <<= 1) {
                    v1 += __shfl_xor(v1, off);
                    v2 += __shfl_xor(v2, off);
                }
                if ((lane & 15) == 0) {
                    int row = row0 + wr * (16 * MT) + m * 16 + (lane >> 4) * 4 + j2;
                    atomicAdd(&s1[h * NN + row], v1);
                    atomicAdd(&s2[h * NN + row], v2);
                }
            }
    }
}

// ---------------------------------------------------------------------------
// k_attn_csr: block per node. Builds neighbor list from adj row n (in LDS),
// writes nbr/cnt, then softmax + aggregate -> xrb. 8-way unrolled gather.
// ---------------------------------------------------------------------------
__global__ __launch_bounds__(256) void k_attn_csr(const float* __restrict__ adj,
                                                  const ushort* __restrict__ Whb,
                                                  const float* __restrict__ s1,
                                                  const float* __restrict__ s2,
                                                  int* __restrict__ nbr,
                                                  int* __restrict__ cnt,
                                                  ushort* __restrict__ xrb) {
    __shared__ int lds_list[4][64];
    __shared__ int lds_cnt[4];
    __shared__ int mlist[CAP];
    __shared__ int stot;
    int n = blockIdx.x;
    int tid = threadIdx.x;
    int wid = tid >> 6;
    int lane = tid & 63;

    const uint4* arow = (const uint4*)(adj + (size_t)n * NN);
    uint4 v[4];
    #pragma unroll
    for (int it = 0; it < 4; ++it) v[it] = arow[wid * 256 + it * 64 + lane];
    const unsigned long long below = (1ull << lane) - 1ull;
    int base = 0;
    #pragma unroll
    for (int it = 0; it < 4; ++it) {
        unsigned long long b0 = __ballot(v[it].x != 0u);
        unsigned long long b1 = __ballot(v[it].y != 0u);
        unsigned long long b2 = __ballot(v[it].z != 0u);
        unsigned long long b3 = __ballot(v[it].w != 0u);
        int pre = __popcll(b0 & below) + __popcll(b1 & below) +
                  __popcll(b2 & below) + __popcll(b3 & below);
        int col0 = wid * 1024 + it * 256 + lane * 4;
        int pos = base + pre;
        if (v[it].x != 0u) { if (pos < 64) lds_list[wid][pos] = col0;     ++pos; }
        if (v[it].y != 0u) { if (pos < 64) lds_list[wid][pos] = col0 + 1; ++pos; }
        if (v[it].z != 0u) { if (pos < 64) lds_list[wid][pos] = col0 + 2; ++pos; }
        if (v[it].w != 0u) { if (pos < 64) lds_list[wid][pos] = col0 + 3; ++pos; }
        base += __popcll(b0) + __popcll(b1) + __popcll(b2) + __popcll(b3);
    }
    if (lane == 0) lds_cnt[wid] = base;
    __syncthreads();
    int c0 = lds_cnt[0], c1 = lds_cnt[1], c2 = lds_cnt[2], c3 = lds_cnt[3];
    {
        int off = (wid > 0 ? c0 : 0) + (wid > 1 ? c1 : 0) + (wid > 2 ? c2 : 0);
        int my = lds_cnt[wid]; if (my > 64) my = 64;
        if (lane < my) {
            int gpos = off + lane;
            if (gpos < CAP) {
                mlist[gpos] = lds_list[wid][lane];
                nbr[n * CAP + gpos] = lds_list[wid][lane];
            }
        }
        if (tid == 0) {
            int tot = c0 + c1 + c2 + c3;
            stot = tot < CAP ? tot : CAP;
            cnt[n] = stot;
        }
    }
    __syncthreads();
    int c = stot;

    int h = wid;
    int m = mlist[lane < c ? lane : 0];
    float e = -1e30f;
    float s1n = s1[h * NN + n];
    if (lane < c) {
        float t = s1n + s2[h * NN + m];
        e = (t >= 0.0f) ? t : ALPHA * t;
    }
    float mx = e;
    #pragma unroll
    for (int off = 32; off; off >>= 1) mx = fmaxf(mx, __shfl_xor(mx, off));
    float p = (lane < c) ? __expf(e - mx) : 0.0f;
    float s = p;
    #pragma unroll
    for (int off = 32; off; off >>= 1) s += __shfl_xor(s, off);
    p /= s;
    // aggregate, 8 independent gathers in flight (p==0 masks j>=c lanes)
    const ushort* wb = Whb + h * 128 + 2 * lane;
    float acc0 = 0.0f, acc1 = 0.0f;
    int cp8 = (c + 7) & ~7;
    for (int j = 0; j < cp8; j += 8) {
        float pj[8]; int mj[8]; unsigned wj[8];
        #pragma unroll
        for (int u = 0; u < 8; ++u) {
            pj[u] = __shfl(p, j + u);
            mj[u] = __shfl(m, j + u);
        }
        #pragma unroll
        for (int u = 0; u < 8; ++u)
            wj[u] = *reinterpret_cast<const unsigned*>(wb + (size_t)mj[u] * 512);
        #pragma unroll
        for (int u = 0; u < 8; ++u) {
            acc0 = fmaf(pj[u], bflo(wj[u]), acc0);
            acc1 = fmaf(pj[u], bfhi(wj[u]), acc1);
        }
    }
    unsigned ow = (unsigned)f2bf(fmaxf(acc0, 0.0f)) | ((unsigned)f2bf(fmaxf(acc1, 0.0f)) << 16);
    *reinterpret_cast<unsigned*>(xrb + (size_t)n * 512 + h * 128 + 2 * lane) = ow;
}

// ---------------------------------------------------------------------------
// Fused: g1 = relu(nbrsum(y1b)); y2 = g1 @ W2. TWO nodes per block —
// all 256 threads active in the gather phase (threads 0-127: node A, 128-255: B)
// ---------------------------------------------------------------------------
__global__ __launch_bounds__(256) void k_g1y2(const ushort* __restrict__ y1b,
                                              const int* __restrict__ nbr,
                                              const int* __restrict__ cnt,
                                              const ushort* __restrict__ W2b,
                                              float* __restrict__ y2) {
    __shared__ float g1s[2][NH2];
    __shared__ float part[2][2][NH3];
    int half = threadIdx.x >> 7;           // node within block
    int t = threadIdx.x & 127;
    int n = blockIdx.x * 2 + half;
    int c = cnt[n];
    const int* nb = nbr + n * CAP;
    {
        float acc0 = 0.0f, acc1 = 0.0f;
        const ushort* yb = y1b + 2 * t;
        for (int j = 0; j < c; j += 8) {
            int idx[8]; float f[8]; unsigned w[8];
            #pragma unroll
            for (int u = 0; u < 8; ++u) {
                idx[u] = nb[(j + u < c) ? j + u : j];
                f[u] = (j + u < c) ? 1.f : 0.f;
            }
            #pragma unroll
            for (int u = 0; u < 8; ++u)
                w[u] = *reinterpret_cast<const unsigned*>(yb + (size_t)idx[u] * NH2);
            #pragma unroll
            for (int u = 0; u < 8; ++u) {
                acc0 = fmaf(f[u], bflo(w[u]), acc0);
                acc1 = fmaf(f[u], bfhi(w[u]), acc1);
            }
        }
        g1s[half][2 * t]     = fmaxf(acc0, 0.0f);
        g1s[half][2 * t + 1] = fmaxf(acc1, 0.0f);
    }
    __syncthreads();
    // y2[n] = g1s[half] @ W2 : 128 threads/node, col = t&63, k-half = t>>6
    int q = t >> 6, col = t & 63;
    float acc = 0.0f;
    #pragma unroll 8
    for (int i = 0; i < 128; ++i) {
        int k = q * 128 + i;
        acc = fmaf(g1s[half][k], bf2f(W2b[k * NH3 + col]), acc);
    }
    part[half][q][col] = acc;
    __syncthreads();
    if (t < 64)
        y2[(size_t)n * NH3 + t] = part[half][0][t] + part[half][1][t];
}

// ---------------------------------------------------------------------------
// final: 4 nodes/block (wave per node); g2 = nbrsum(y2); out = [g2, softmax]
// ---------------------------------------------------------------------------
__global__ __launch_bounds__(256) void k_final(const float* __restrict__ Y2,
                                               const int* __restrict__ nbr,
                                               const int* __restrict__ cnt,
                                               float* __restrict__ out) {
    int n = blockIdx.x * 4 + (threadIdx.x >> 6);
    int lane = threadIdx.x & 63;
    int c = cnt[n];
    const int* nb = nbr + n * CAP;
    float acc = 0.0f;
    for (int j = 0; j < c; j += 8) {
        int idx[8]; float f[8]; float v[8];
        #pragma unroll
        for (int u = 0; u < 8; ++u) {
            idx[u] = nb[(j + u < c) ? j + u : j];
            f[u] = (j + u < c) ? 1.f : 0.f;
        }
        #pragma unroll
        for (int u = 0; u < 8; ++u)
            v[u] = Y2[(size_t)idx[u] * NH3 + lane];
        #pragma unroll
        for (int u = 0; u < 8; ++u)
            acc = fmaf(f[u], v[u], acc);
    }
    out[(size_t)n * NH3 + lane] = acc;
    float mx = acc;
    #pragma unroll
    for (int off = 32; off; off >>= 1) mx = fmaxf(mx, __shfl_xor(mx, off));
    float p = __expf(acc - mx);
    float s = p;
    #pragma unroll
    for (int off = 32; off; off >>= 1) s += __shfl_xor(s, off);
    out[(size_t)NN * NH3 + (size_t)n * NH3 + lane] = p / s;
}

// ---------------------------------------------------------------------------
extern "C" void kernel_launch(void* const* d_in, const int* in_sizes, int n_in,
                              void* d_out, int out_size, void* d_ws, size_t ws_size,
                              hipStream_t stream) {
    const float* x     = (const float*)d_in[0];   // (4096, 512)
    const float* adj   = (const float*)d_in[1];   // (4096, 4096)
    const float* W_att = (const float*)d_in[2];   // (4, 512, 128)
    const float* a     = (const float*)d_in[3];   // (4, 256)
    const float* W1    = (const float*)d_in[4];   // (512, 256)
    const float* W2    = (const float*)d_in[5];   // (256, 64)
    float* out = (float*)d_out;

    char* p = (char*)d_ws;
    ushort* xb    = (ushort*)p; p += (size_t)NN * FIN * 2;           // 4 MB
    ushort* Wattb = (ushort*)p; p += (size_t)FIN * NH * NH1 * 2;     // 0.5 MB
    ushort* W1t   = (ushort*)p; p += (size_t)NH2 * (NH * NH1) * 2;   // 0.25 MB
    ushort* W2b   = (ushort*)p; p += (size_t)NH2 * NH3 * 2;          // 32 KB
    ushort* Whb   = (ushort*)p; p += (size_t)NN * NH * NH1 * 2;      // 4 MB
    float*  s1    = (float*)p;  p += (size_t)NH * NN * 4;
    float*  s2    = (float*)p;  p += (size_t)NH * NN * 4;
    int*    nbr   = (int*)p;    p += (size_t)NN * CAP * 4;           // 1 MB
    int*    cnt   = (int*)p;    p += (size_t)NN * 4;
    ushort* xrb   = (ushort*)p; p += (size_t)NN * NH * NH1 * 2;      // 4 MB
    ushort* y1b   = (ushort*)p; p += (size_t)NN * NH2 * 2;           // 2 MB
    float*  y2    = (float*)p;  p += (size_t)NN * NH3 * 4;           // 1 MB

    // A: conversions + zero s1/s2
    k_conv<<<C_Z, 256, 0, stream>>>(x, xb, W_att, Wattb, W1, W1t, W2, W2b, s1);
    // B: Whb(bf16) = x @ Wcat + fused s1/s2 scores (BM=64; 512 blocks, XCD-coherent)
    k_gemm<1, 2, 6><<<512, 256, 0, stream>>>(
        xb, Wattb, Whb, a, s1, s2, NN, NH * NH1, FIN);
    // C: CSR(row-local) + attention -> xrb ; writes nbr/cnt for D/E
    k_attn_csr<<<NN, 256, 0, stream>>>(adj, Whb, s1, s2, nbr, cnt, xrb);
    // D: y1b = xr @ W1  (BM=32; 512 blocks, XCD-coherent)
    k_gemm<0, 1, 7><<<512, 256, 0, stream>>>(
        xrb, W1t, y1b, nullptr, nullptr, nullptr, NN, NH2, NH * NH1);
    // E: g1 = relu(nbrsum(y1b)); y2 = g1 @ W2  (2 nodes/block)
    k_g1y2<<<NN / 2, 256, 0, stream>>>(y1b, nbr, cnt, W2b, y2);
    // F: g2 + softmax (4 nodes/block)
    k_final<<<NN / 4, 256, 0, stream>>>(y2, nbr, cnt, out);
}